// Round 9
// baseline (113.193 us; speedup 1.0000x reference)
//
#include <hip/hip_runtime.h>
#include <math.h>

namespace {
constexpr int Bc = 2, Hc = 224, Wc = 224, HWc = Hc * Wc;
constexpr int COUTc = 64, PADc = 3;
constexpr int MIXc = 4, RELc = 32;
constexpr int PHc = 230, PWc = 230;
constexpr int FHc = 112, FWc = 112, NN = FHc * FWc;  // 12544
constexpr int NK = 49;
constexpr int CH = 32;                               // pixels per chunk
constexpr int NCH = NN / CH;                         // 392
// ws float offsets
constexpr int WS_EEX = 0;                            // [4][230]
constexpr int WS_EEY = WS_EEX + MIXc * PWc;          // [4][230]
constexpr int WS_PART = WS_EEY + MIXc * PHc;         // [B][49][392]
constexpr int WS_E = WS_PART + Bc * NK * NCH;        // [B][49][NN] exp(score)
}

// Collapsed weights into sCol[51]: M[9], Rx[21], Ry[21]. Threads 0..50.
__device__ __forceinline__ void collapse(const float* __restrict__ wq,
                                         const float* __restrict__ wk,
                                         const float* __restrict__ rx,
                                         const float* __restrict__ ry,
                                         float* sCol) {
  const int t = threadIdx.x;
  if (t < 51) {
    float s = 0.f;
    if (t < 9) {
      const int cj = t / 3, ci = t % 3;
#pragma unroll 8
      for (int o = 0; o < COUTc; ++o) s += wq[cj * COUTc + o] * wk[ci * COUTc + o];
    } else if (t < 30) {
      const int v = t - 9, cj = v / 7, kw = v % 7;
#pragma unroll 8
      for (int o = 0; o < RELc; ++o) s += wq[cj * COUTc + o] * rx[o * 7 + kw];
    } else {
      const int v = t - 30, cj = v / 7, kh = v % 7;
#pragma unroll 8
      for (int o = 0; o < RELc; ++o) s += wq[cj * COUTc + RELc + o] * ry[o * 7 + kh];
    }
    sCol[t] = s;
  }
}

// ---- K1: scores -> exp table E + per-chunk denominator partials + tables.
// grid (392, 2), block 256 = 32 px x 8 tap-groups.
__global__ __launch_bounds__(256) void sam_scores(
    const float* __restrict__ x, const float* __restrict__ wq,
    const float* __restrict__ wk, const float* __restrict__ rx,
    const float* __restrict__ ry, const float* __restrict__ ex,
    const float* __restrict__ ey, const float* __restrict__ em,
    float* __restrict__ ws) {
  __shared__ float sCol[51];
  const int t = threadIdx.x;
  const int c = blockIdx.x, b = blockIdx.y;
  collapse(wq, wk, rx, ry, sCol);

  // Blocks 0..7 also fill the mixture tables (consumed only by K2).
  const int bf = b * NCH + c;
  if (bf < 8) {
    const int idx = bf * 256 + t;
    constexpr int half = MIXc * PWc;
    if (idx < 2 * half) {
      const int which = idx >= half;
      const int r = which ? idx - half : idx;
      const int m = r / PWc, j = r % PWc;
      float s = 0.f;
#pragma unroll 8
      for (int cc = 0; cc < COUTc; ++cc)
        s += (which ? ey[cc * PHc + j] : ex[cc * PWc + j]) * em[m * COUTc + cc];
      ws[idx] = __expf(s);
    }
  }
  __syncthreads();

  const int g = t >> 5, px = t & 31;
  const int n = c * CH + px;
  const int fh = n / FWc, fw = n - fh * FWc;
  const int i0 = 2 * fh, j0 = 2 * fw;
  const float* xb = x + (size_t)b * 3 * HWc;
  const int co = i0 * Wc + j0;
  const float xc0 = xb[co], xc1 = xb[HWc + co], xc2 = xb[2 * HWc + co];
  const float q0 = xc0 * sCol[0] + xc1 * sCol[3] + xc2 * sCol[6];
  const float q1 = xc0 * sCol[1] + xc1 * sCol[4] + xc2 * sCol[7];
  const float q2 = xc0 * sCol[2] + xc1 * sCol[5] + xc2 * sCol[8];

  float* E = ws + WS_E;
  float* part = ws + WS_PART;
#pragma unroll
  for (int it = 0; it < 7; ++it) {
    const int kk = g + 8 * it;
    if (kk < NK) {
      const int kh = kk / 7, kw = kk - 7 * kh;
      float s = xc0 * (sCol[9 + kw] + sCol[30 + kh]) +
                xc1 * (sCol[16 + kw] + sCol[37 + kh]) +
                xc2 * (sCol[23 + kw] + sCol[44 + kh]);
      const int ir = i0 + kh - PADc, jc = j0 + kw - PADc;
      if ((unsigned)ir < (unsigned)Hc && (unsigned)jc < (unsigned)Wc) {
        const int off = ir * Wc + jc;
        s += q0 * xb[off] + q1 * xb[HWc + off] + q2 * xb[2 * HWc + off];
      }
      const float e = __expf(s);
      E[(size_t)(b * NK + kk) * NN + n] = e;
      float r = e;  // reduce within the 32-px half-wave
      r += __shfl_xor(r, 1, 64);
      r += __shfl_xor(r, 2, 64);
      r += __shfl_xor(r, 4, 64);
      r += __shfl_xor(r, 8, 64);
      r += __shfl_xor(r, 16, 64);
      if (px == 0) part[(b * NK + kk) * NCH + c] = r;
    }
  }
}

// ---- K2: denominators + mixture-weighted accumulation + projection.
// grid (392, 2), block 256 = 32 px x 8 tap-groups.
__global__ __launch_bounds__(256) void sam_out(
    const float* __restrict__ x, const float* __restrict__ wv,
    const float* __restrict__ bias, const float* __restrict__ ws,
    float* __restrict__ out) {
  __shared__ float sEEX[MIXc * PWc];
  __shared__ float sEEY[MIXc * PHc];
  __shared__ float sdninv[NK];
  __shared__ float swv[12 * 64];
  __shared__ float sbias[64];
  __shared__ float sT[8][32][13];

  const int t = threadIdx.x;
  const int c = blockIdx.x, b = blockIdx.y;
  for (int i = t; i < MIXc * PWc; i += 256) sEEX[i] = ws[WS_EEX + i];
  for (int i = t; i < MIXc * PHc; i += 256) sEEY[i] = ws[WS_EEY + i];
  if (t < 64) sbias[t] = bias[t];
  for (int i = t; i < 12 * 64; i += 256) swv[i] = wv[i];
  if (t < 4 * NK) {  // 4 threads per k over 392 partials
    const int k = t >> 2, p = t & 3;
    const float* base = ws + WS_PART + (b * NK + k) * NCH;
    float s = 0.f;
    for (int cc = p; cc < NCH; cc += 4) s += base[cc];
    s += __shfl_xor(s, 1, 64);
    s += __shfl_xor(s, 2, 64);
    if (p == 0) sdninv[k] = 1.f / s;
  }
  __syncthreads();

  const int g = t >> 5, px = t & 31;
  const int n = c * CH + px;
  const int fh = n / FWc, fw = n - fh * FWc;
  const int i0 = 2 * fh, j0 = 2 * fw;
  const float* xb = x + (size_t)b * 3 * HWc;
  const float* E = ws + WS_E;

  float T[12] = {0.f};  // [m*3+ci], static indexing only
#pragma unroll
  for (int it = 0; it < 7; ++it) {
    const int kk = g + 8 * it;
    if (kk < NK) {
      const int kh = kk / 7, kw = kk - 7 * kh;
      const int ir = i0 + kh - PADc, jc = j0 + kw - PADc;
      if ((unsigned)ir < (unsigned)Hc && (unsigned)jc < (unsigned)Wc) {
        const float e = E[(size_t)(b * NK + kk) * NN + n] * sdninv[kk];
        const int ii = i0 + kh, jj = j0 + kw;
        const float p0 = sEEX[jj] * sEEY[ii];
        const float p1 = sEEX[PWc + jj] * sEEY[PHc + ii];
        const float p2 = sEEX[2 * PWc + jj] * sEEY[2 * PHc + ii];
        const float p3 = sEEX[3 * PWc + jj] * sEEY[3 * PHc + ii];
        const float wgt = e * __builtin_amdgcn_rcpf(p0 + p1 + p2 + p3);
        const int off = ir * Wc + jc;
        const float x0 = xb[off], x1 = xb[HWc + off], x2 = xb[2 * HWc + off];
        const float a0 = wgt * p0, a1 = wgt * p1, a2 = wgt * p2, a3 = wgt * p3;
        T[0] += a0 * x0; T[1]  += a0 * x1; T[2]  += a0 * x2;
        T[3] += a1 * x0; T[4]  += a1 * x1; T[5]  += a1 * x2;
        T[6] += a2 * x0; T[7]  += a2 * x1; T[8]  += a2 * x2;
        T[9] += a3 * x0; T[10] += a3 * x1; T[11] += a3 * x2;
      }
    }
  }
#pragma unroll
  for (int j = 0; j < 12; ++j) sT[g][px][j] = T[j];
  __syncthreads();

  float Tm[12];
#pragma unroll
  for (int j = 0; j < 12; ++j) {
    float s = 0.f;
#pragma unroll
    for (int ww = 0; ww < 8; ++ww) s += sT[ww][px][j];
    Tm[j] = s;
  }
  float* ob = out + (size_t)b * COUTc * NN + n;
#pragma unroll
  for (int oo = 0; oo < 8; ++oo) {
    const int o = g * 8 + oo;
    float acc = sbias[o];
#pragma unroll
    for (int mc = 0; mc < 12; ++mc) acc += swv[mc * 64 + o] * Tm[mc];
    ob[(size_t)o * NN] = acc;
  }
}

extern "C" void kernel_launch(void* const* d_in, const int* in_sizes, int n_in,
                              void* d_out, int out_size, void* d_ws, size_t ws_size,
                              hipStream_t stream) {
  const float* x    = (const float*)d_in[0];
  const float* wq   = (const float*)d_in[1];
  const float* wk   = (const float*)d_in[2];
  const float* wv   = (const float*)d_in[3];
  const float* rx   = (const float*)d_in[4];
  const float* ry   = (const float*)d_in[5];
  const float* ex   = (const float*)d_in[6];
  const float* ey   = (const float*)d_in[7];
  const float* em   = (const float*)d_in[8];
  const float* bias = (const float*)d_in[9];
  float* out = (float*)d_out;
  float* ws  = (float*)d_ws;

  sam_scores<<<dim3(NCH, Bc), 256, 0, stream>>>(x, wq, wk, rx, ry, ex, ey, em, ws);
  sam_out<<<dim3(NCH, Bc), 256, 0, stream>>>(x, wv, bias, ws, out);
}